// Round 7
// baseline (86.862 us; speedup 1.0000x reference)
//
#include <hip/hip_runtime.h>
#include <cstdint>

#define CIN    512
#define COUT   32
#define IMH    56
#define IMW    56
#define NB     32
#define CHUNKS 16
#define XSTR   40          // shorts per pixel (32 k + 8 pad) = 80 B
#define NTH    512         // 8 waves
#define YT     7           // 8-row output tiles (1.25x halo)
#define SLOTS  2240        // 10 rows x 14 xg x 16 c2
#define SPT    5           // ceil(2240/512)
#define BUFS   (10 * 58 * XSTR)  // 23200 shorts = 46400 B per LDS buffer

typedef __attribute__((ext_vector_type(8))) short v8s;   // 8 bf16 = 4 VGPRs
typedef __attribute__((ext_vector_type(4))) float v4f;

__device__ __forceinline__ unsigned short f2bf(float f) {
    unsigned u = __builtin_bit_cast(unsigned, f);
    u += 0x7FFFu + ((u >> 16) & 1u);          // round-to-nearest-even
    return (unsigned short)(u >> 16);
}

// ---------------------------------------------------------------------------
// Weight transform (fp32 OIHW -> bf16 MFMA A-frag order) + BN const table.
// w2[(((gc*9+tap)*2+mt)*64+lane)*8+j] = W[m=mt*16+(lane&15)][k=gc*32+(lane>>4)*8+j][tap]
// bq[gc*16+c2] = {scale0, shift0, scale1, shift1} for channels gc*32+2*c2, +1
// ---------------------------------------------------------------------------
__global__ void wtransform(const float* __restrict__ cw,
                           const float* __restrict__ bn_w, const float* __restrict__ bn_b,
                           const float* __restrict__ rm,   const float* __restrict__ rv,
                           unsigned short* __restrict__ w2, float4* __restrict__ bq) {
    int idx = blockIdx.x * blockDim.x + threadIdx.x;
    if (idx < 256) {
        int c = idx * 2;
        float s0 = bn_w[c]     * rsqrtf(rv[c]     + 1e-5f);
        float s1 = bn_w[c + 1] * rsqrtf(rv[c + 1] + 1e-5f);
        bq[idx] = make_float4(s0, bn_b[c] - rm[c] * s0, s1, bn_b[c + 1] - rm[c + 1] * s1);
    }
    if (idx >= CHUNKS * 9 * 2 * 64 * 8) return;
    int j    = idx & 7;
    int lane = (idx >> 3) & 63;
    int mt   = (idx >> 9) & 1;
    int tmp  = idx >> 10;
    int tap  = tmp % 9;
    int gc   = tmp / 9;
    int m = mt * 16 + (lane & 15);
    int k = gc * 32 + (lane >> 4) * 8 + j;
    w2[idx] = f2bf(cw[((size_t)m * CIN + k) * 9 + tap]);
}

// ---------------------------------------------------------------------------
// One-pass fused BN+ReLU+3x3 conv, tap-decomposed MFMA implicit GEMM.
// R5: raw s_barrier (lgkmcnt(0) only) -> prefetch survives the barrier.
// R6: depth-2 ping-pong input prefetch.  R7: BN constants in LDS.
// R8: stacked 8x2 tiles w/ rolling tap-row reuse, cvt_pk bf16 pack.
// R9: XCD-aware block remap (halo rows shared via per-XCD L2).
// R10 (merged pack+MFMA region) REGRESSED +5us -> reverted to R9 structure.
// R11: SIMD-balanced tile assignment.  R8's 7-active-wave scheme put
// waves {0,4}{1,5}{2,6}{3} on SIMDs 0-3 -> SIMD0-2 carry 8 tiles each,
// SIMD3 only 4: MFMA phase paced by the 8-tile SIMDs (~1.16us) while
// SIMD3 idles half.  New: waves 0-3 = full columns 0-3 (4 chained tiles),
// waves 4-6 = rows 0-5 of columns 4-6 (3 chained tiles), wave 7 = the
// three bottom tiles (rows 6-7, cols 4-6, fresh reads).  7 tiles/SIMD
// everywhere; MFMA total unchanged (504); reads 189->198 (+5%, still
// under the matrix term).
// ---------------------------------------------------------------------------
struct SlotTab {
    int lbase[SPT];
    int gofs[SPT];
    int actm;            // bit j = slot exists && input row valid
};

__device__ __forceinline__ void load_inputs(const float* __restrict__ p0,
                                            const SlotTab& st,
                                            float4 (&va)[SPT], float4 (&vb)[SPT]) {
    #pragma unroll
    for (int j = 0; j < SPT; ++j) {
        if (st.actm & (1 << j)) {
            const float* p = p0 + st.gofs[j];
            va[j] = *(const float4*)p;
            vb[j] = *(const float4*)(p + 3136);
        }
    }
}

__device__ __forceinline__ unsigned cvtpk(float lo, float hi) {
    unsigned r;
    asm("v_cvt_pk_bf16_f32 %0, %1, %2" : "=v"(r) : "v"(lo), "v"(hi));
    return r;
}

__device__ __forceinline__ void pack_chunk(unsigned short* __restrict__ bp,
                                           const SlotTab& st, float4 bn,
                                           const float4 (&va)[SPT], const float4 (&vb)[SPT]) {
    #pragma unroll
    for (int j = 0; j < SPT; ++j) {
        if (st.actm & (1 << j)) {
            float a0 = fmaxf(fmaf(va[j].x, bn.x, bn.y), 0.f);
            float a1 = fmaxf(fmaf(va[j].y, bn.x, bn.y), 0.f);
            float a2 = fmaxf(fmaf(va[j].z, bn.x, bn.y), 0.f);
            float a3 = fmaxf(fmaf(va[j].w, bn.x, bn.y), 0.f);
            float b0 = fmaxf(fmaf(vb[j].x, bn.z, bn.w), 0.f);
            float b1 = fmaxf(fmaf(vb[j].y, bn.z, bn.w), 0.f);
            float b2 = fmaxf(fmaf(vb[j].z, bn.z, bn.w), 0.f);
            float b3 = fmaxf(fmaf(vb[j].w, bn.z, bn.w), 0.f);
            unsigned u0 = cvtpk(a0, b0);   // lo = even channel, hi = odd
            unsigned u1 = cvtpk(a1, b1);
            unsigned u2 = cvtpk(a2, b2);
            unsigned u3 = cvtpk(a3, b3);
            int base = st.lbase[j];
            *(unsigned*)&bp[base]            = u0;
            *(unsigned*)&bp[base + XSTR]     = u1;
            *(unsigned*)&bp[base + 2 * XSTR] = u2;
            *(unsigned*)&bp[base + 3 * XSTR] = u3;
        }
    }
}

// Chained MFMA (waves 0-6): ntile stacked 8x2 tiles in one column; tile t's
// ty=0 row equals tile t-1's ty=2 row -> rolling 3-reg reuse.
// Tap (ty,tx) of tile t reads bp[tb[t] + (ty*58+tx)*XSTR].
__device__ __forceinline__ void mfma_chain(const unsigned short* __restrict__ bp,
                                           const v8s (&aw0)[9], const v8s (&aw1)[9],
                                           const int (&tb)[4], int ntile,
                                           v4f (&acc)[4][2]) {
    v8s sav0, sav1, sav2;
    #pragma unroll
    for (int t = 0; t < 4; ++t) {
        if (t < ntile) {
            #pragma unroll
            for (int ty = 0; ty < 3; ++ty) {
                #pragma unroll
                for (int tx = 0; tx < 3; ++tx) {
                    v8s b;
                    if (ty == 0 && t > 0) {
                        b = (tx == 0) ? sav0 : (tx == 1) ? sav1 : sav2;
                    } else {
                        b = *(const v8s*)&bp[tb[t] + (ty * 58 + tx) * XSTR];
                    }
                    if (ty == 2) {
                        if (tx == 0) sav0 = b; else if (tx == 1) sav1 = b; else sav2 = b;
                    }
                    const int tap = ty * 3 + tx;
                    acc[t][0] = __builtin_amdgcn_mfma_f32_16x16x32_bf16(aw0[tap], b, acc[t][0], 0, 0, 0);
                    acc[t][1] = __builtin_amdgcn_mfma_f32_16x16x32_bf16(aw1[tap], b, acc[t][1], 0, 0, 0);
                }
            }
        }
    }
}

// Fresh MFMA (wave 7): 3 independent bottom tiles (rows 6-7 of cols 4-6).
__device__ __forceinline__ void mfma_fresh(const unsigned short* __restrict__ bp,
                                           const v8s (&aw0)[9], const v8s (&aw1)[9],
                                           const int (&tb)[4],
                                           v4f (&acc)[4][2]) {
    #pragma unroll
    for (int t = 0; t < 3; ++t) {
        #pragma unroll
        for (int ty = 0; ty < 3; ++ty) {
            #pragma unroll
            for (int tx = 0; tx < 3; ++tx) {
                v8s b = *(const v8s*)&bp[tb[t] + (ty * 58 + tx) * XSTR];
                const int tap = ty * 3 + tx;
                acc[t][0] = __builtin_amdgcn_mfma_f32_16x16x32_bf16(aw0[tap], b, acc[t][0], 0, 0, 0);
                acc[t][1] = __builtin_amdgcn_mfma_f32_16x16x32_bf16(aw1[tap], b, acc[t][1], 0, 0, 0);
            }
        }
    }
}

// one chunk: weights(gc) -> pack(gc) -> issue inputs(gc+2) -> barrier -> MFMA
__device__ __forceinline__ void do_chunk(int gc, const float* __restrict__ xn,
                                         const unsigned short* __restrict__ w2,
                                         const float4* __restrict__ s_bq,
                                         unsigned short* __restrict__ bp,
                                         const SlotTab& st,
                                         float4 (&va)[SPT], float4 (&vb)[SPT],
                                         const int (&tb)[4], int wv, int ntile,
                                         v4f (&acc)[4][2], int c2, int lane,
                                         bool prefetch) {
    // weights for chunk gc from L1/L2; MFMA's counted wait leaves the
    // input prefetch below in flight
    v8s aw0[9], aw1[9];
    const v8s* wpv = (const v8s*)(w2 + (size_t)gc * 9216);
    #pragma unroll
    for (int t = 0; t < 9; ++t) {
        aw0[t] = wpv[t * 128 + lane];
        aw1[t] = wpv[t * 128 + 64 + lane];
    }

    // BN constants from LDS (lgkm counter — no vmem drain)
    float4 bn = s_bq[gc * 16 + c2];

    // pack chunk gc — inputs issued two chunks ago (arrived: no wait)
    pack_chunk(bp, st, bn, va, vb);

    // re-issue this register set with chunk gc+2's inputs; stays in
    // flight across the barrier and the whole next chunk
    if (prefetch)
        load_inputs(xn + (size_t)(gc + 2) * 32 * 3136, st, va, vb);

    // raw barrier: drain LDS ops only, leave global prefetch in flight
    asm volatile("s_waitcnt lgkmcnt(0)" ::: "memory");
    __builtin_amdgcn_s_barrier();

    // MFMA chunk gc — SIMD-balanced tile sets (wave-uniform branch)
    if (wv < 7) mfma_chain(bp, aw0, aw1, tb, ntile, acc);
    else        mfma_fresh(bp, aw0, aw1, tb, acc);
}

__global__ __launch_bounds__(NTH, 1)
void conv_mfma(const float* __restrict__ x,
               const unsigned short* __restrict__ w2,
               const float4* __restrict__ bq,
               float* __restrict__ out)
{
    __shared__ __align__(16) unsigned short s_x[2][BUFS];   // 92800 B
    __shared__ __align__(16) float4 s_bq[CHUNKS * 16];      // 4096 B

    const int tid  = threadIdx.x;
    const int lane = tid & 63;
    const int wv   = tid >> 6;          // 0..7

    // --- R9: XCD-aware remap (XCD = bid%8 round-robin) ---
    const int bid = blockIdx.x;          // 0..223
    const int k8  = bid & 7;
    const int q   = bid >> 3;            // 0..27
    const int n   = k8 + 8 * (q / 7);    // 0..31
    const int yt  = q % 7;               // 0..6
    const int y0   = yt * 8;
    const int c2   = tid & 15;

    // --- stage BN constant table into LDS (one-time, 4 KB) ---
    if (tid < CHUNKS * 16) s_bq[tid] = bq[tid];

    // --- slot tables: slot = tid + j*512 -> (c2, xg, row r=0..9) ---
    SlotTab st;
    st.actm = 0;
    #pragma unroll
    for (int j = 0; j < SPT; ++j) {
        int slot = tid + j * NTH;
        bool inr = (slot < SLOTS);
        int rest = slot >> 4;
        int xg = rest % 14;
        int r  = rest / 14;              // 0..9
        int iy = y0 - 1 + r;
        bool v = inr && (iy >= 0) && (iy < IMH);
        if (v) st.actm |= (1 << j);
        st.lbase[j] = (r * 58 + xg * 4 + 1) * XSTR + c2 * 2;
        st.gofs[j]  = c2 * 2 * 3136 + (v ? iy : 0) * 56 + xg * 4;
    }

    // --- prezero halo cols (px 0,57), all 10 rows, both buffers ---
    for (int i = tid; i < 2 * 10 * 2 * 20; i += NTH) {
        int kq = i % 20;
        int t  = i / 20;                 // buf(2) x row(10) x side(2)
        int side = t & 1;
        int r  = (t >> 1) % 10;
        int b  = t / 20;
        *(unsigned*)&s_x[b][(r * 58 + (side ? 57 : 0)) * XSTR + kq * 2] = 0u;
    }
    // --- prezero invalid rows (top/bottom blocks), both buffers; pack skips them ---
    if (yt == 0 || yt == YT - 1) {
        int r = (yt == 0) ? 0 : 9;
        for (int i = tid; i < 2 * 58 * 20; i += NTH) {
            int b = i >= 58 * 20;
            int q2 = i - b * 58 * 20;
            *(unsigned*)&s_x[b][r * 58 * XSTR + q2 * 2] = 0u;
        }
    }

    // --- SIMD-balanced tiles: 7 tiles per SIMD.
    //     waves 0-3: column wv (8 px wide), rows 0-7  -> 4 chained tiles
    //     waves 4-6: column wv, rows 0-5              -> 3 chained tiles
    //     wave 7:    rows 6-7 of columns 4,5,6        -> 3 fresh tiles ---
    const int ntile = (wv < 4) ? 4 : 3;
    const int dy  = (lane & 15) >> 3;
    const int px8 = lane & 7;
    int tb[4];
    #pragma unroll
    for (int t = 0; t < 4; ++t) {
        int col, ii;
        if (wv < 7) { col = wv;                 ii = (t < ntile) ? t : 0; }
        else        { col = 4 + ((t < 3) ? t : 0); ii = 3; }
        tb[t] = ((2 * ii + dy) * 58 + col * 8 + px8) * XSTR + (lane >> 4) * 8;
    }
    v4f acc[4][2];
    const v4f zero4 = {0.f, 0.f, 0.f, 0.f};
    #pragma unroll
    for (int i = 0; i < 4; ++i) { acc[i][0] = zero4; acc[i][1] = zero4; }

    const float* xn = x + (size_t)n * CIN * 3136;

    // --- prologue: depth-2 prefetch — chunk 0 -> set A, chunk 1 -> set B ---
    float4 vaA[SPT], vbA[SPT], vaB[SPT], vbB[SPT];
    load_inputs(xn, st, vaA, vbA);
    load_inputs(xn + (size_t)32 * 3136, st, vaB, vbB);

    // s_bq + prezero visibility; raw barrier leaves prefetch in flight
    asm volatile("s_waitcnt lgkmcnt(0)" ::: "memory");
    __builtin_amdgcn_s_barrier();

    // unrolled x2 so the A/B register sets have compile-time identity
    for (int gc = 0; gc < CHUNKS; gc += 2) {
        do_chunk(gc,     xn, w2, s_bq, &s_x[0][0], st, vaA, vbA,
                 tb, wv, ntile, acc, c2, lane, gc + 2 < CHUNKS);
        do_chunk(gc + 1, xn, w2, s_bq, &s_x[1][0], st, vaB, vbB,
                 tb, wv, ntile, acc, c2, lane, gc + 3 < CHUNKS);
    }

    // --- epilogue: direct stores ---
    const int prow = (lane >> 4) * 4;
    #pragma unroll
    for (int t = 0; t < 4; ++t) {
        if (t >= ntile) break;
        int py, px;
        if (wv < 7) { py = 2 * t + dy; px = wv * 8 + px8; }
        else        { py = 6 + dy;     px = (4 + t) * 8 + px8; }
        size_t o0 = (size_t)n * COUT * 3136 + (size_t)(y0 + py) * 56 + px;
        #pragma unroll
        for (int mt = 0; mt < 2; ++mt) {
            #pragma unroll
            for (int r = 0; r < 4; ++r) {
                int cout = mt * 16 + prow + r;
                out[o0 + (size_t)cout * 3136] = acc[t][mt][r];
            }
        }
    }
}

extern "C" void kernel_launch(void* const* d_in, const int* in_sizes, int n_in,
                              void* d_out, int out_size, void* d_ws, size_t ws_size,
                              hipStream_t stream) {
    const float* x      = (const float*)d_in[0];
    const float* bn_w   = (const float*)d_in[2];
    const float* bn_b   = (const float*)d_in[3];
    const float* r_mean = (const float*)d_in[4];
    const float* r_var  = (const float*)d_in[5];
    const float* cw     = (const float*)d_in[6];
    float* out = (float*)d_out;

    unsigned short* w2 = (unsigned short*)d_ws;                  // 294912 B
    float4* bq = (float4*)((char*)d_ws + 294912);                // 4096 B

    wtransform<<<dim3(576), dim3(256), 0, stream>>>(cw, bn_w, bn_b, r_mean, r_var, w2, bq);

    conv_mfma<<<dim3(YT * NB), dim3(NTH), 0, stream>>>(x, w2, bq, out);
}

// Round 8
// 71.348 us; speedup vs baseline: 1.2174x; 1.2174x over previous
//
#include <hip/hip_runtime.h>
#include <cstdint>

#define CIN    512
#define COUT   32
#define IMH    56
#define IMW    56
#define NB     32
#define CHUNKS 16
#define XSTR   40          // shorts per pixel (32 k + 8 pad) = 80 B
#define NTH    512         // 8 waves
#define YT     7           // 8-row output tiles (1.25x halo)
#define SLOTS  2240        // 10 rows x 14 xg x 16 c2
#define SPT    5           // ceil(2240/512)
#define BUFS   (10 * 58 * XSTR)  // 23200 shorts = 46400 B per LDS buffer

typedef __attribute__((ext_vector_type(8))) short v8s;   // 8 bf16 = 4 VGPRs
typedef __attribute__((ext_vector_type(4))) float v4f;

__device__ __forceinline__ unsigned short f2bf(float f) {
    unsigned u = __builtin_bit_cast(unsigned, f);
    u += 0x7FFFu + ((u >> 16) & 1u);          // round-to-nearest-even
    return (unsigned short)(u >> 16);
}

// ---------------------------------------------------------------------------
// Weight transform (fp32 OIHW -> bf16 MFMA A-frag order) + BN const table.
// R12: one u32 (j-pair) per thread — coalesced 4B stores, half the threads.
// w2 u32 layout identical to the short layout:
//   w2[(((gc*9+tap)*2+mt)*64+lane)*8+j] = W[m=mt*16+(lane&15)][k=gc*32+(lane>>4)*8+j][tap]
// bq[gc*16+c2] = {scale0, shift0, scale1, shift1} for channels gc*32+2*c2, +1
// ---------------------------------------------------------------------------
__global__ void wtransform(const float* __restrict__ cw,
                           const float* __restrict__ bn_w, const float* __restrict__ bn_b,
                           const float* __restrict__ rm,   const float* __restrict__ rv,
                           unsigned* __restrict__ w2u, float4* __restrict__ bq) {
    int idx = blockIdx.x * blockDim.x + threadIdx.x;   // 0..73727 (u32 index)
    if (idx < 256) {
        int c = idx * 2;
        float s0 = bn_w[c]     * rsqrtf(rv[c]     + 1e-5f);
        float s1 = bn_w[c + 1] * rsqrtf(rv[c + 1] + 1e-5f);
        bq[idx] = make_float4(s0, bn_b[c] - rm[c] * s0, s1, bn_b[c + 1] - rm[c + 1] * s1);
    }
    if (idx >= CHUNKS * 9 * 2 * 64 * 4) return;
    int jp   = idx & 3;          // j pair: j = 2*jp, 2*jp+1
    int lane = (idx >> 2) & 63;
    int mt   = (idx >> 8) & 1;
    int tmp  = idx >> 9;
    int tap  = tmp % 9;
    int gc   = tmp / 9;
    int m = mt * 16 + (lane & 15);
    int k = gc * 32 + (lane >> 4) * 8 + 2 * jp;
    const float* base = &cw[((size_t)m * CIN + k) * 9 + tap];
    unsigned lo = f2bf(base[0]);     // k   (j even)
    unsigned hi = f2bf(base[9]);     // k+1 (j odd) — k stride in cw is 9 floats
    w2u[idx] = lo | (hi << 16);
}

// ---------------------------------------------------------------------------
// One-pass fused BN+ReLU+3x3 conv, tap-decomposed MFMA implicit GEMM.
// R5: raw s_barrier (lgkmcnt(0) only) -> prefetch survives the barrier.
// R6: depth-2 ping-pong input prefetch.  R7: BN constants in LDS.
// R8: stacked 8x2 tiles w/ rolling tap-row reuse, cvt_pk bf16 pack.
// R9: XCD-aware block remap (halo rows shared via per-XCD L2).  <- BEST
// R10 (merged pack+MFMA region) +5us and R11 (SIMD-balanced dual-path
// MFMA) +15us both REGRESSED -> conv reverted to the exact R9 body.
// Lesson: in this 1-block/CU lockstep structure only strict-subset
// micro-cuts pay; added code paths / live ranges hit a codegen cliff.
// ---------------------------------------------------------------------------
struct SlotTab {
    int lbase[SPT];
    int gofs[SPT];
    int actm;            // bit j = slot exists && input row valid
};

__device__ __forceinline__ void load_inputs(const float* __restrict__ p0,
                                            const SlotTab& st,
                                            float4 (&va)[SPT], float4 (&vb)[SPT]) {
    #pragma unroll
    for (int j = 0; j < SPT; ++j) {
        if (st.actm & (1 << j)) {
            const float* p = p0 + st.gofs[j];
            va[j] = *(const float4*)p;
            vb[j] = *(const float4*)(p + 3136);
        }
    }
}

__device__ __forceinline__ unsigned cvtpk(float lo, float hi) {
    unsigned r;
    asm("v_cvt_pk_bf16_f32 %0, %1, %2" : "=v"(r) : "v"(lo), "v"(hi));
    return r;
}

__device__ __forceinline__ void pack_chunk(unsigned short* __restrict__ bp,
                                           const SlotTab& st, float4 bn,
                                           const float4 (&va)[SPT], const float4 (&vb)[SPT]) {
    #pragma unroll
    for (int j = 0; j < SPT; ++j) {
        if (st.actm & (1 << j)) {
            float a0 = fmaxf(fmaf(va[j].x, bn.x, bn.y), 0.f);
            float a1 = fmaxf(fmaf(va[j].y, bn.x, bn.y), 0.f);
            float a2 = fmaxf(fmaf(va[j].z, bn.x, bn.y), 0.f);
            float a3 = fmaxf(fmaf(va[j].w, bn.x, bn.y), 0.f);
            float b0 = fmaxf(fmaf(vb[j].x, bn.z, bn.w), 0.f);
            float b1 = fmaxf(fmaf(vb[j].y, bn.z, bn.w), 0.f);
            float b2 = fmaxf(fmaf(vb[j].z, bn.z, bn.w), 0.f);
            float b3 = fmaxf(fmaf(vb[j].w, bn.z, bn.w), 0.f);
            unsigned u0 = cvtpk(a0, b0);   // lo = even channel, hi = odd
            unsigned u1 = cvtpk(a1, b1);
            unsigned u2 = cvtpk(a2, b2);
            unsigned u3 = cvtpk(a3, b3);
            int base = st.lbase[j];
            *(unsigned*)&bp[base]            = u0;
            *(unsigned*)&bp[base + XSTR]     = u1;
            *(unsigned*)&bp[base + 2 * XSTR] = u2;
            *(unsigned*)&bp[base + 3 * XSTR] = u3;
        }
    }
}

// Stacked-tile MFMA: tile i covers output rows (2i, 2i+1) of the 8-row
// block, cols [8*wv .. 8*wv+7].  Lane n=lane&15 -> (dy=n>>3, px8=n&7).
// Tap (ty,tx) reads LDS short addr pbase + ((2i+ty)*58 + tx)*XSTR where
// pbase = (dy*58 + 8*wv + px8)*XSTR + (lane>>4)*8.
__device__ __forceinline__ void mfma_chunk(const unsigned short* __restrict__ bp,
                                           const v8s (&aw0)[9], const v8s (&aw1)[9],
                                           int pbase, bool active,
                                           v4f (&acc)[4][2]) {
    if (!active) return;
    v8s sav0, sav1, sav2;
    #pragma unroll
    for (int i = 0; i < 4; ++i) {
        #pragma unroll
        for (int ty = 0; ty < 3; ++ty) {
            #pragma unroll
            for (int tx = 0; tx < 3; ++tx) {
                v8s b;
                if (ty == 0 && i > 0) {
                    b = (tx == 0) ? sav0 : (tx == 1) ? sav1 : sav2;
                } else {
                    b = *(const v8s*)&bp[pbase + ((2 * i + ty) * 58 + tx) * XSTR];
                }
                if (ty == 2) {
                    if (tx == 0) sav0 = b; else if (tx == 1) sav1 = b; else sav2 = b;
                }
                const int tap = ty * 3 + tx;
                acc[i][0] = __builtin_amdgcn_mfma_f32_16x16x32_bf16(aw0[tap], b, acc[i][0], 0, 0, 0);
                acc[i][1] = __builtin_amdgcn_mfma_f32_16x16x32_bf16(aw1[tap], b, acc[i][1], 0, 0, 0);
            }
        }
    }
}

// one chunk: weights(gc) -> pack(gc) -> issue inputs(gc+2) -> barrier -> MFMA
__device__ __forceinline__ void do_chunk(int gc, const float* __restrict__ xn,
                                         const unsigned short* __restrict__ w2,
                                         const float4* __restrict__ s_bq,
                                         unsigned short* __restrict__ bp,
                                         const SlotTab& st,
                                         float4 (&va)[SPT], float4 (&vb)[SPT],
                                         int pbase, bool active,
                                         v4f (&acc)[4][2], int c2, int lane,
                                         bool prefetch) {
    // weights for chunk gc from L1/L2; MFMA's counted wait leaves the
    // input prefetch below in flight
    v8s aw0[9], aw1[9];
    const v8s* wpv = (const v8s*)(w2 + (size_t)gc * 9216);
    #pragma unroll
    for (int t = 0; t < 9; ++t) {
        aw0[t] = wpv[t * 128 + lane];
        aw1[t] = wpv[t * 128 + 64 + lane];
    }

    // BN constants from LDS (lgkm counter — no vmem drain)
    float4 bn = s_bq[gc * 16 + c2];

    // pack chunk gc — inputs issued two chunks ago (arrived: no wait)
    pack_chunk(bp, st, bn, va, vb);

    // re-issue this register set with chunk gc+2's inputs; stays in
    // flight across the barrier and the whole next chunk
    if (prefetch)
        load_inputs(xn + (size_t)(gc + 2) * 32 * 3136, st, va, vb);

    // raw barrier: drain LDS ops only, leave global prefetch in flight
    asm volatile("s_waitcnt lgkmcnt(0)" ::: "memory");
    __builtin_amdgcn_s_barrier();

    mfma_chunk(bp, aw0, aw1, pbase, active, acc);
}

__global__ __launch_bounds__(NTH, 1)
void conv_mfma(const float* __restrict__ x,
               const unsigned short* __restrict__ w2,
               const float4* __restrict__ bq,
               float* __restrict__ out)
{
    __shared__ __align__(16) unsigned short s_x[2][BUFS];   // 92800 B
    __shared__ __align__(16) float4 s_bq[CHUNKS * 16];      // 4096 B

    const int tid  = threadIdx.x;
    const int lane = tid & 63;
    const int wv   = tid >> 6;          // 0..7

    // --- R9: XCD-aware remap (XCD = bid%8 round-robin) ---
    const int bid = blockIdx.x;          // 0..223
    const int k8  = bid & 7;
    const int q   = bid >> 3;            // 0..27
    const int n   = k8 + 8 * (q / 7);    // 0..31
    const int yt  = q % 7;               // 0..6
    const int y0   = yt * 8;
    const int c2   = tid & 15;

    // --- stage BN constant table into LDS (one-time, 4 KB) ---
    if (tid < CHUNKS * 16) s_bq[tid] = bq[tid];

    // --- slot tables: slot = tid + j*512 -> (c2, xg, row r=0..9) ---
    SlotTab st;
    st.actm = 0;
    #pragma unroll
    for (int j = 0; j < SPT; ++j) {
        int slot = tid + j * NTH;
        bool inr = (slot < SLOTS);
        int rest = slot >> 4;
        int xg = rest % 14;
        int r  = rest / 14;              // 0..9
        int iy = y0 - 1 + r;
        bool v = inr && (iy >= 0) && (iy < IMH);
        if (v) st.actm |= (1 << j);
        st.lbase[j] = (r * 58 + xg * 4 + 1) * XSTR + c2 * 2;
        st.gofs[j]  = c2 * 2 * 3136 + (v ? iy : 0) * 56 + xg * 4;
    }

    // --- prezero halo cols (px 0,57), all 10 rows, both buffers ---
    for (int i = tid; i < 2 * 10 * 2 * 20; i += NTH) {
        int kq = i % 20;
        int t  = i / 20;                 // buf(2) x row(10) x side(2)
        int side = t & 1;
        int r  = (t >> 1) % 10;
        int b  = t / 20;
        *(unsigned*)&s_x[b][(r * 58 + (side ? 57 : 0)) * XSTR + kq * 2] = 0u;
    }
    // --- prezero invalid rows (top/bottom blocks), both buffers; pack skips them ---
    if (yt == 0 || yt == YT - 1) {
        int r = (yt == 0) ? 0 : 9;
        for (int i = tid; i < 2 * 58 * 20; i += NTH) {
            int b = i >= 58 * 20;
            int q2 = i - b * 58 * 20;
            *(unsigned*)&s_x[b][r * 58 * XSTR + q2 * 2] = 0u;
        }
    }

    // --- stacked tiles: wave wv<7 owns cols [8wv..8wv+7] x all 8 rows ---
    const bool active = (wv < 7);
    const int dy  = (lane & 15) >> 3;
    const int px8 = lane & 7;
    const int pbase = (dy * 58 + wv * 8 + px8) * XSTR + (lane >> 4) * 8;
    v4f acc[4][2];
    const v4f zero4 = {0.f, 0.f, 0.f, 0.f};
    #pragma unroll
    for (int i = 0; i < 4; ++i) { acc[i][0] = zero4; acc[i][1] = zero4; }

    const float* xn = x + (size_t)n * CIN * 3136;

    // --- prologue: depth-2 prefetch — chunk 0 -> set A, chunk 1 -> set B ---
    float4 vaA[SPT], vbA[SPT], vaB[SPT], vbB[SPT];
    load_inputs(xn, st, vaA, vbA);
    load_inputs(xn + (size_t)32 * 3136, st, vaB, vbB);

    // s_bq + prezero visibility; raw barrier leaves prefetch in flight
    asm volatile("s_waitcnt lgkmcnt(0)" ::: "memory");
    __builtin_amdgcn_s_barrier();

    // unrolled x2 so the A/B register sets have compile-time identity
    for (int gc = 0; gc < CHUNKS; gc += 2) {
        do_chunk(gc,     xn, w2, s_bq, &s_x[0][0], st, vaA, vbA,
                 pbase, active, acc, c2, lane, gc + 2 < CHUNKS);
        do_chunk(gc + 1, xn, w2, s_bq, &s_x[1][0], st, vaB, vbB,
                 pbase, active, acc, c2, lane, gc + 3 < CHUNKS);
    }

    // --- epilogue: direct stores (tile i -> rows 2i,2i+1 of the block) ---
    if (active) {
        const int prow = (lane >> 4) * 4;
        #pragma unroll
        for (int i = 0; i < 4; ++i) {
            int py = 2 * i + dy;
            int px = wv * 8 + px8;
            size_t o0 = (size_t)n * COUT * 3136 + (size_t)(y0 + py) * 56 + px;
            #pragma unroll
            for (int mt = 0; mt < 2; ++mt) {
                #pragma unroll
                for (int r = 0; r < 4; ++r) {
                    int cout = mt * 16 + prow + r;
                    out[o0 + (size_t)cout * 3136] = acc[i][mt][r];
                }
            }
        }
    }
}

extern "C" void kernel_launch(void* const* d_in, const int* in_sizes, int n_in,
                              void* d_out, int out_size, void* d_ws, size_t ws_size,
                              hipStream_t stream) {
    const float* x      = (const float*)d_in[0];
    const float* bn_w   = (const float*)d_in[2];
    const float* bn_b   = (const float*)d_in[3];
    const float* r_mean = (const float*)d_in[4];
    const float* r_var  = (const float*)d_in[5];
    const float* cw     = (const float*)d_in[6];
    float* out = (float*)d_out;

    unsigned short* w2 = (unsigned short*)d_ws;                  // 294912 B
    float4* bq = (float4*)((char*)d_ws + 294912);                // 4096 B

    // R12: 73728 u32 elements, 288 blocks x 256 threads
    wtransform<<<dim3(288), dim3(256), 0, stream>>>(cw, bn_w, bn_b, r_mean, r_var,
                                                    (unsigned*)w2, bq);

    conv_mfma<<<dim3(YT * NB), dim3(NTH), 0, stream>>>(x, w2, bq, out);
}